// Round 2
// baseline (515.741 us; speedup 1.0000x reference)
//
#include <hip/hip_runtime.h>
#include <cstdint>
#include <cstddef>

// Problem constants (fixed by reference setup_inputs)
#define BATCH 8
#define CH    128
#define NPTS  65536
#define NOBJ  64
#define TPB   256
#define PPT   4                 // points per thread (float4)
#define PPB   (TPB * PPT)       // 1024 points per block

// Monotonic order-preserving encode: larger float -> larger uint.
// f >= 0: bits | 0x80000000 ; f < 0: ~bits.  Encoded 0 only for -NaN,
// so 0 is a safe "empty" sentinel (identity for max).
__device__ __forceinline__ uint32_t enc_f32(float f) {
    uint32_t x = __float_as_uint(f);
    return x ^ ((uint32_t)((int32_t)x >> 31) | 0x80000000u);
}

__global__ __launch_bounds__(256) void init_out_kernel(uint32_t* __restrict__ out, int n) {
    int i = blockIdx.x * blockDim.x + threadIdx.x;
    if (i < n) out[i] = 0u;
}

__global__ __launch_bounds__(TPB) void seg_max_kernel(
        const float* __restrict__ pf,      // (B, C, N)
        const int*   __restrict__ bidx,    // (B, N) in [0, NOBJ)
        uint32_t*    __restrict__ out)     // (B*NOBJ, C) encoded
{
    // Accumulator [c][seg]: within one channel's wave of atomics, bank = seg%32
    // -> random spread (~2-way aliasing, free per m136).
    __shared__ uint32_t acc[CH * NOBJ];    // 32 KiB

    const int tid   = threadIdx.x;
    const int b     = blockIdx.x / (NPTS / PPB);
    const int chunk = blockIdx.x % (NPTS / PPB);
    const int n0    = chunk * PPB;

    #pragma unroll
    for (int i = tid; i < CH * NOBJ; i += TPB) acc[i] = 0u;
    __syncthreads();

    // Segment ids for this thread's 4 consecutive points (coalesced int4).
    const int4 sv = *(const int4*)(bidx + (size_t)b * NPTS + n0 + tid * PPT);
    const int s0 = sv.x, s1 = sv.y, s2 = sv.z, s3 = sv.w;

    const float* p = pf + (size_t)b * CH * NPTS + n0 + tid * PPT;
    uint32_t* row = acc;

    #pragma unroll 4
    for (int c = 0; c < CH; ++c, p += NPTS, row += NOBJ) {
        const float4 v = *(const float4*)p;   // 16B coalesced
        atomicMax(&row[s0], enc_f32(v.x));
        atomicMax(&row[s1], enc_f32(v.y));
        atomicMax(&row[s2], enc_f32(v.z));
        atomicMax(&row[s3], enc_f32(v.w));
    }
    __syncthreads();

    // Merge block-local maxes into global (device-scope atomics).
    for (int e = tid; e < CH * NOBJ; e += TPB) {
        const int seg = e & (NOBJ - 1);
        const int c   = e >> 6;
        const uint32_t v = acc[c * NOBJ + seg];
        if (v) atomicMax(&out[(size_t)(b * NOBJ + seg) * CH + c], v);
    }
}

__global__ __launch_bounds__(256) void finalize_kernel(uint32_t* __restrict__ out, int n) {
    int i = blockIdx.x * blockDim.x + threadIdx.x;
    if (i >= n) return;
    const uint32_t u = out[i];
    float f = 0.0f;
    if (u != 0u) {
        // decode: top bit set -> was positive: x = u ^ 0x80000000; else x = ~u
        const uint32_t x = u ^ ((uint32_t)((int32_t)(~u) >> 31) | 0x80000000u);
        f = __uint_as_float(x);
        if (!isfinite(f)) f = 0.0f;   // reference's empty/-inf guard
    }
    ((float*)out)[i] = f;
}

extern "C" void kernel_launch(void* const* d_in, const int* in_sizes, int n_in,
                              void* d_out, int out_size, void* d_ws, size_t ws_size,
                              hipStream_t stream) {
    const float* pf   = (const float*)d_in[0];
    const int*   bidx = (const int*)d_in[1];
    uint32_t*    out  = (uint32_t*)d_out;

    const int nOut = out_size;  // B*NOBJ*CH = 65536

    // 1) init output to encoded -infinity sentinel (0)
    init_out_kernel<<<(nOut + 255) / 256, 256, 0, stream>>>(out, nOut);

    // 2) scatter segment-max: 8 batches x 64 chunks = 512 blocks
    const int blocks = BATCH * (NPTS / PPB);
    seg_max_kernel<<<blocks, TPB, 0, stream>>>(pf, bidx, out);

    // 3) decode + guard
    finalize_kernel<<<(nOut + 255) / 256, 256, 0, stream>>>(out, nOut);
}

// Round 3
// 374.901 us; speedup vs baseline: 1.3757x; 1.3757x over previous
//
#include <hip/hip_runtime.h>
#include <cstdint>
#include <cstddef>

// Problem constants (fixed by reference setup_inputs)
#define BATCH 8
#define CH    128
#define NPTS  65536
#define NOBJ  64
#define TPB   256
#define SEGEL (CH * NOBJ)   // 8192 partial elements per block

// Monotonic order-preserving encode: larger float -> larger uint.
// Encoded 0 only arises from -NaN, so 0 is a safe empty sentinel.
__device__ __forceinline__ uint32_t enc_f32(float f) {
    uint32_t x = __float_as_uint(f);
    return x ^ ((uint32_t)((int32_t)x >> 31) | 0x80000000u);
}
__device__ __forceinline__ float dec_f32(uint32_t u) {
    uint32_t x = u ^ ((uint32_t)((int32_t)(~u) >> 31) | 0x80000000u);
    return __uint_as_float(x);
}

// ---------------------------------------------------------------------------
// Main path: LDS-privatized segment max, partials to workspace (no atomics
// past LDS). NCHUNK = partial blocks per batch. PPB = NPTS/NCHUNK points.
// Lane mapping inside a wave: c_local = lane>>4 (4 channels per instr),
// pq = lane&15 (16 float4 quads). One ds_atomic instruction touches
// 4 channels x 16 random segs -> few same-address collisions; XOR swizzle
// s^(c&3) splits duplicated segs across banks.
// ---------------------------------------------------------------------------
template <int NCHUNK>
__global__ __launch_bounds__(TPB) void seg_max_ws(
        const float* __restrict__ pf,     // (B, C, N)
        const int*   __restrict__ bidx,   // (B, N)
        uint32_t*    __restrict__ ws)     // (B*NCHUNK, SEGEL) encoded partials
{
    constexpr int PPB = NPTS / NCHUNK;    // points per block
    constexpr int J   = PPB / 256;        // passes per channel-iteration

    __shared__ uint32_t acc[SEGEL];       // 32 KiB, layout [c][s ^ (c&3)]

    const int tid  = threadIdx.x;
    const int wave = tid >> 6;
    const int lane = tid & 63;
    const int cl   = lane >> 4;           // channel-local 0..3 (thread-constant)
    const int pq   = lane & 15;

    const int b     = blockIdx.x / NCHUNK;
    const int chunk = blockIdx.x % NCHUNK;
    const int n0    = chunk * PPB;

    for (int i = tid; i < SEGEL; i += TPB) acc[i] = 0u;

    // Preload this thread's segment ids (J passes x 4 points), pre-swizzled.
    int s[J][4];
    #pragma unroll
    for (int j = 0; j < J; ++j) {
        const int q = j * 64 + wave * 16 + pq;          // float4-quad index
        const int4 sv = *(const int4*)(bidx + (size_t)b * NPTS + n0 + q * 4);
        s[j][0] = sv.x ^ cl;  s[j][1] = sv.y ^ cl;
        s[j][2] = sv.z ^ cl;  s[j][3] = sv.w ^ cl;
    }
    __syncthreads();

    const float* pbase = pf + (size_t)b * CH * NPTS + n0;

    for (int cb = 0; cb < CH; cb += 4) {
        const int c = cb + cl;
        const float* pc = pbase + (size_t)c * NPTS;
        float4 v[J];
        #pragma unroll
        for (int j = 0; j < J; ++j) {
            const int q = j * 64 + wave * 16 + pq;
            v[j] = *(const float4*)(pc + q * 4);        // 4x256B segments/wave
        }
        uint32_t* row = acc + c * NOBJ;
        #pragma unroll
        for (int j = 0; j < J; ++j) {
            atomicMax(&row[s[j][0]], enc_f32(v[j].x));
            atomicMax(&row[s[j][1]], enc_f32(v[j].y));
            atomicMax(&row[s[j][2]], enc_f32(v[j].z));
            atomicMax(&row[s[j][3]], enc_f32(v[j].w));
        }
    }
    __syncthreads();

    // Coalesced non-atomic partial dump.
    uint32_t* wsb = ws + (size_t)blockIdx.x * SEGEL;
    for (int e = tid; e < SEGEL; e += TPB) wsb[e] = acc[e];
}

// Max over the per-chunk partials + decode + finite guard. Writes every
// output element exactly once (no init kernel needed).
template <int NCHUNK>
__global__ __launch_bounds__(256) void reduce_ws(
        const uint32_t* __restrict__ ws, float* __restrict__ out)
{
    const int g = blockIdx.x * 256 + threadIdx.x;   // 0 .. B*SEGEL-1
    const int b = g >> 13;                          // batch (SEGEL = 8192)
    const int e = g & (SEGEL - 1);                  // stored index in partial
    const uint32_t* p = ws + (size_t)b * NCHUNK * SEGEL + e;
    uint32_t m = 0u;
    #pragma unroll 8
    for (int k = 0; k < NCHUNK; ++k) m = max(m, p[(size_t)k * SEGEL]);
    const int c   = e >> 6;
    const int seg = (e & 63) ^ (c & 3);             // un-swizzle
    float f = 0.0f;
    if (m) { f = dec_f32(m); if (!isfinite(f)) f = 0.0f; }
    out[(size_t)(b * NOBJ + seg) * CH + c] = f;
}

// ---------------------------------------------------------------------------
// Fallback path (ws too small): R2 structure with global-atomic merge.
// ---------------------------------------------------------------------------
__global__ __launch_bounds__(256) void init_out_kernel(uint32_t* __restrict__ out, int n) {
    int i = blockIdx.x * blockDim.x + threadIdx.x;
    if (i < n) out[i] = 0u;
}

__global__ __launch_bounds__(TPB) void seg_max_atomic(
        const float* __restrict__ pf, const int* __restrict__ bidx,
        uint32_t* __restrict__ out)
{
    constexpr int PPB = 1024;
    __shared__ uint32_t acc[SEGEL];
    const int tid   = threadIdx.x;
    const int b     = blockIdx.x / (NPTS / PPB);
    const int chunk = blockIdx.x % (NPTS / PPB);
    const int n0    = chunk * PPB;
    for (int i = tid; i < SEGEL; i += TPB) acc[i] = 0u;
    __syncthreads();
    const int4 sv = *(const int4*)(bidx + (size_t)b * NPTS + n0 + tid * 4);
    const float* p = pf + (size_t)b * CH * NPTS + n0 + tid * 4;
    uint32_t* row = acc;
    #pragma unroll 4
    for (int c = 0; c < CH; ++c, p += NPTS, row += NOBJ) {
        const float4 v = *(const float4*)p;
        atomicMax(&row[sv.x], enc_f32(v.x));
        atomicMax(&row[sv.y], enc_f32(v.y));
        atomicMax(&row[sv.z], enc_f32(v.z));
        atomicMax(&row[sv.w], enc_f32(v.w));
    }
    __syncthreads();
    for (int e = tid; e < SEGEL; e += TPB) {
        const int seg = e & (NOBJ - 1);
        const int c   = e >> 6;
        const uint32_t v = acc[c * NOBJ + seg];
        if (v) atomicMax(&out[(size_t)(b * NOBJ + seg) * CH + c], v);
    }
}

__global__ __launch_bounds__(256) void finalize_kernel(uint32_t* __restrict__ out, int n) {
    int i = blockIdx.x * blockDim.x + threadIdx.x;
    if (i >= n) return;
    const uint32_t u = out[i];
    float f = 0.0f;
    if (u) { f = dec_f32(u); if (!isfinite(f)) f = 0.0f; }
    ((float*)out)[i] = f;
}

extern "C" void kernel_launch(void* const* d_in, const int* in_sizes, int n_in,
                              void* d_out, int out_size, void* d_ws, size_t ws_size,
                              hipStream_t stream) {
    const float* pf   = (const float*)d_in[0];
    const int*   bidx = (const int*)d_in[1];

    const size_t need128 = (size_t)BATCH * 128 * SEGEL * 4;  // 32 MiB
    const size_t need64  = (size_t)BATCH *  64 * SEGEL * 4;  // 16 MiB

    if (ws_size >= need128) {
        uint32_t* ws = (uint32_t*)d_ws;
        seg_max_ws<128><<<BATCH * 128, TPB, 0, stream>>>(pf, bidx, ws);
        reduce_ws<128><<<(BATCH * SEGEL) / 256, 256, 0, stream>>>(ws, (float*)d_out);
    } else if (ws_size >= need64) {
        uint32_t* ws = (uint32_t*)d_ws;
        seg_max_ws<64><<<BATCH * 64, TPB, 0, stream>>>(pf, bidx, ws);
        reduce_ws<64><<<(BATCH * SEGEL) / 256, 256, 0, stream>>>(ws, (float*)d_out);
    } else {
        uint32_t* out = (uint32_t*)d_out;
        init_out_kernel<<<(out_size + 255) / 256, 256, 0, stream>>>(out, out_size);
        seg_max_atomic<<<BATCH * (NPTS / 1024), TPB, 0, stream>>>(pf, bidx, out);
        finalize_kernel<<<(out_size + 255) / 256, 256, 0, stream>>>(out, out_size);
    }
}

// Round 4
// 367.842 us; speedup vs baseline: 1.4021x; 1.0192x over previous
//
#include <hip/hip_runtime.h>
#include <cstdint>
#include <cstddef>

// Problem constants (fixed by reference setup_inputs)
#define BATCH 8
#define CH    128
#define NPTS  65536
#define NOBJ  64
#define TPB   256
#define SEGEL (CH * NOBJ)   // 8192 accumulator elements per block

// Monotonic order-preserving encode: larger float -> larger uint.
// Encoded 0 only arises from -NaN, so 0 is a safe empty sentinel.
__device__ __forceinline__ uint32_t enc_f32(float f) {
    uint32_t x = __float_as_uint(f);
    return x ^ ((uint32_t)((int32_t)x >> 31) | 0x80000000u);
}
__device__ __forceinline__ float dec_f32(uint32_t u) {
    uint32_t x = u ^ ((uint32_t)((int32_t)(~u) >> 31) | 0x80000000u);
    return __uint_as_float(x);
}

// ---------------------------------------------------------------------------
// seg_max_ws: LDS-privatized segment max, software-pipelined.
// Lane map: cl = lane>>3 (8 channels per instr), pq = lane&7 (8 float4 quads).
// One ds_atomic instr = 8 channels x 8 random segs -> ~3.4 same-address
// collisions (halved vs 4x16 map). Loads: 8 x 128B contiguous segments.
// Pipeline: loads for channel-block cb+8 issue BEFORE atomics for cb, so
// HBM latency overlaps the LDS-atomic work.
// Swizzle: acc[c][s ^ (c&7)]; since cb % 8 == 0, (cb+cl)&7 == cl, so the
// per-thread swizzled seg ids are loop-invariant.
// ---------------------------------------------------------------------------
template <int NCHUNK>
__global__ __launch_bounds__(TPB) void seg_max_ws(
        const float* __restrict__ pf,     // (B, C, N)
        const int*   __restrict__ bidx,   // (B, N)
        uint32_t*    __restrict__ ws)     // (B*NCHUNK, SEGEL) encoded partials
{
    constexpr int PPB = NPTS / NCHUNK;    // points per block
    constexpr int J   = PPB / 4 / 32;     // load passes (32 quads per pass)
    static_assert(J >= 1, "chunk too small");

    __shared__ uint32_t acc[SEGEL];       // 32 KiB

    const int tid  = threadIdx.x;
    const int wave = tid >> 6;
    const int lane = tid & 63;
    const int cl   = lane >> 3;           // channel-local 0..7
    const int pq   = lane & 7;            // quad-local 0..7

    const int b     = blockIdx.x / NCHUNK;
    const int chunk = blockIdx.x % NCHUNK;
    const int n0    = chunk * PPB;

    for (int i = tid; i < SEGEL; i += TPB) acc[i] = 0u;

    // Pre-swizzled segment ids for this thread's J*4 points.
    int s[J][4];
    #pragma unroll
    for (int j = 0; j < J; ++j) {
        const int q = j * 32 + wave * 8 + pq;
        const int4 sv = *(const int4*)(bidx + (size_t)b * NPTS + n0 + q * 4);
        s[j][0] = sv.x ^ cl;  s[j][1] = sv.y ^ cl;
        s[j][2] = sv.z ^ cl;  s[j][3] = sv.w ^ cl;
    }
    __syncthreads();

    const float* pbase = pf + (size_t)b * CH * NPTS + n0;
    const int qoff = (wave * 8 + pq) * 4;

    float4 v[J], vn[J];
    {
        const float* pc = pbase + (size_t)cl * NPTS;
        #pragma unroll
        for (int j = 0; j < J; ++j) v[j] = *(const float4*)(pc + j * 128 + qoff);
    }

    for (int cb = 0; cb < CH; cb += 8) {
        if (cb + 8 < CH) {   // wave-uniform branch
            const float* pn = pbase + (size_t)(cb + 8 + cl) * NPTS;
            #pragma unroll
            for (int j = 0; j < J; ++j) vn[j] = *(const float4*)(pn + j * 128 + qoff);
        }
        uint32_t* row = acc + (cb + cl) * NOBJ;
        #pragma unroll
        for (int j = 0; j < J; ++j) {
            atomicMax(&row[s[j][0]], enc_f32(v[j].x));
            atomicMax(&row[s[j][1]], enc_f32(v[j].y));
            atomicMax(&row[s[j][2]], enc_f32(v[j].z));
            atomicMax(&row[s[j][3]], enc_f32(v[j].w));
        }
        #pragma unroll
        for (int j = 0; j < J; ++j) v[j] = vn[j];
    }
    __syncthreads();

    // Coalesced non-atomic partial dump.
    uint32_t* wsb = ws + (size_t)blockIdx.x * SEGEL;
    for (int e = tid; e < SEGEL; e += TPB) wsb[e] = acc[e];
}

// Max over per-chunk partials + decode + finite guard. Writes every output
// element exactly once. Fully unrolled so the strided L2/L3 loads pipeline.
template <int NCHUNK>
__global__ __launch_bounds__(256) void reduce_ws(
        const uint32_t* __restrict__ ws, float* __restrict__ out)
{
    const int g = blockIdx.x * 256 + threadIdx.x;   // 0 .. B*SEGEL-1
    const int b = g >> 13;                          // SEGEL = 8192
    const int e = g & (SEGEL - 1);
    const uint32_t* p = ws + (size_t)b * NCHUNK * SEGEL + e;
    uint32_t m = 0u;
    #pragma unroll
    for (int k = 0; k < NCHUNK; ++k) m = max(m, p[(size_t)k * SEGEL]);
    const int c   = e >> 6;
    const int seg = (e & 63) ^ (c & 7);             // un-swizzle
    float f = 0.0f;
    if (m) { f = dec_f32(m); if (!isfinite(f)) f = 0.0f; }
    out[(size_t)(b * NOBJ + seg) * CH + c] = f;
}

// ---------------------------------------------------------------------------
// Fallback path (ws too small): global-atomic merge.
// ---------------------------------------------------------------------------
__global__ __launch_bounds__(256) void init_out_kernel(uint32_t* __restrict__ out, int n) {
    int i = blockIdx.x * blockDim.x + threadIdx.x;
    if (i < n) out[i] = 0u;
}

__global__ __launch_bounds__(TPB) void seg_max_atomic(
        const float* __restrict__ pf, const int* __restrict__ bidx,
        uint32_t* __restrict__ out)
{
    constexpr int PPB = 1024;
    __shared__ uint32_t acc[SEGEL];
    const int tid   = threadIdx.x;
    const int b     = blockIdx.x / (NPTS / PPB);
    const int chunk = blockIdx.x % (NPTS / PPB);
    const int n0    = chunk * PPB;
    for (int i = tid; i < SEGEL; i += TPB) acc[i] = 0u;
    __syncthreads();
    const int4 sv = *(const int4*)(bidx + (size_t)b * NPTS + n0 + tid * 4);
    const float* p = pf + (size_t)b * CH * NPTS + n0 + tid * 4;
    uint32_t* row = acc;
    #pragma unroll 4
    for (int c = 0; c < CH; ++c, p += NPTS, row += NOBJ) {
        const float4 v = *(const float4*)p;
        atomicMax(&row[sv.x], enc_f32(v.x));
        atomicMax(&row[sv.y], enc_f32(v.y));
        atomicMax(&row[sv.z], enc_f32(v.z));
        atomicMax(&row[sv.w], enc_f32(v.w));
    }
    __syncthreads();
    for (int e = tid; e < SEGEL; e += TPB) {
        const int seg = e & (NOBJ - 1);
        const int c   = e >> 6;
        const uint32_t v = acc[c * NOBJ + seg];
        if (v) atomicMax(&out[(size_t)(b * NOBJ + seg) * CH + c], v);
    }
}

__global__ __launch_bounds__(256) void finalize_kernel(uint32_t* __restrict__ out, int n) {
    int i = blockIdx.x * blockDim.x + threadIdx.x;
    if (i >= n) return;
    const uint32_t u = out[i];
    float f = 0.0f;
    if (u) { f = dec_f32(u); if (!isfinite(f)) f = 0.0f; }
    ((float*)out)[i] = f;
}

extern "C" void kernel_launch(void* const* d_in, const int* in_sizes, int n_in,
                              void* d_out, int out_size, void* d_ws, size_t ws_size,
                              hipStream_t stream) {
    const float* pf   = (const float*)d_in[0];
    const int*   bidx = (const int*)d_in[1];

    const size_t need128 = (size_t)BATCH * 128 * SEGEL * 4;  // 32 MiB
    const size_t need64  = (size_t)BATCH *  64 * SEGEL * 4;  // 16 MiB

    if (ws_size >= need128) {
        uint32_t* ws = (uint32_t*)d_ws;
        seg_max_ws<128><<<BATCH * 128, TPB, 0, stream>>>(pf, bidx, ws);
        reduce_ws<128><<<(BATCH * SEGEL) / 256, 256, 0, stream>>>(ws, (float*)d_out);
    } else if (ws_size >= need64) {
        uint32_t* ws = (uint32_t*)d_ws;
        seg_max_ws<64><<<BATCH * 64, TPB, 0, stream>>>(pf, bidx, ws);
        reduce_ws<64><<<(BATCH * SEGEL) / 256, 256, 0, stream>>>(ws, (float*)d_out);
    } else {
        uint32_t* out = (uint32_t*)d_out;
        init_out_kernel<<<(out_size + 255) / 256, 256, 0, stream>>>(out, out_size);
        seg_max_atomic<<<BATCH * (NPTS / 1024), TPB, 0, stream>>>(pf, bidx, out);
        finalize_kernel<<<(out_size + 255) / 256, 256, 0, stream>>>(out, out_size);
    }
}